// Round 4
// baseline (533.095 us; speedup 1.0000x reference)
//
#include <hip/hip_runtime.h>

typedef unsigned short u16;
typedef unsigned int   u32;
typedef float  floatx4 __attribute__((ext_vector_type(4)));
typedef __bf16 bfx8    __attribute__((ext_vector_type(8)));
typedef u16    u16x8   __attribute__((ext_vector_type(8)));
typedef u32    u32x4   __attribute__((ext_vector_type(4)));

#define DEV __device__ __forceinline__

// Problem constants: B=4, C=256, Ch=128, N=H*W=4096
#define NB 4
#define NC 256
#define NCH 128
#define NSP 4096
#define OUT_OFF 4194304   // floats: 4*256*4096 out region precedes attn region

DEV u16 f2bf(float f) {
  u32 u = __builtin_bit_cast(u32, f);
  u = (u + 0x7fffu + ((u >> 16) & 1u)) >> 16;   // round-to-nearest-even
  return (u16)u;
}

DEV float bf2f(u16 h) {
  u32 w = (u32)h << 16;
  return __builtin_bit_cast(float, w);
}

DEV void lds_load16(const u16* g, u16* l) {
  __builtin_amdgcn_global_load_lds(
      (const __attribute__((address_space(1))) u32*)g,
      (__attribute__((address_space(3))) u32*)l, 16, 0, 0);
}

DEV floatx4 mfma16(bfx8 a, bfx8 b, floatx4 c) {
  return __builtin_amdgcn_mfma_f32_16x16x32_bf16(a, b, c, 0, 0, 0);
}

// ------------- fused weight converter + prep (one launch) -------------------
__global__ __launch_bounds__(256) void cvt_all(
    const float* __restrict__ wf1, const float* __restrict__ wg1,
    const float* __restrict__ wf2, const float* __restrict__ wg2,
    const float* __restrict__ wh,
    u16* __restrict__ wfg1b, u16* __restrict__ wfg2b, u16* __restrict__ whb,
    const float* __restrict__ bf1, const float* __restrict__ bg1,
    const float* __restrict__ bf2, const float* __restrict__ bg2,
    float* __restrict__ bfg1, float* __restrict__ bfg2) {
  int i = blockIdx.x * 256 + threadIdx.x;
  if (i < 32768) { wfg1b[i] = f2bf(wf1[i]); return; }
  i -= 32768;
  if (i < 32768) { wfg1b[32768 + i] = f2bf(wg1[i]); return; }
  i -= 32768;
  if (i < 16384) { wfg2b[i] = f2bf(wf2[i]); return; }
  i -= 16384;
  if (i < 16384) { wfg2b[16384 + i] = f2bf(wg2[i]); return; }
  i -= 16384;
  if (i < 65536) { whb[i] = f2bf(wh[i]); return; }
  i -= 65536;
  if (i < 128) { bfg1[i] = bf1[i]; return; }
  i -= 128;
  if (i < 128) { bfg1[128 + i] = bg1[i]; return; }
  i -= 128;
  if (i < 128) { bfg2[i] = bf2[i]; return; }
  i -= 128;
  if (i < 128) { bfg2[128 + i] = bg2[i]; return; }
}

// x (B,C,N) fp32 -> xT (B,N,C) bf16
__global__ __launch_bounds__(256) void transpose_x(const float* __restrict__ x,
                                                   u16* __restrict__ xT) {
  __shared__ float T[64 * 65];
  const int b = blockIdx.z, c0 = blockIdx.y * 64, n0 = blockIdx.x * 64;
  const int tid = threadIdx.x;
  const int j = tid & 63, r0 = tid >> 6;
  const size_t xbase = ((size_t)b * NC + c0) * NSP + n0;
  #pragma unroll
  for (int s = 0; s < 16; s++) {
    int cl = s * 4 + r0;
    T[cl * 65 + j] = x[xbase + (size_t)cl * NSP + j];
  }
  __syncthreads();
  const size_t tbase = ((size_t)b * NSP + n0) * NC + c0;
  #pragma unroll
  for (int s = 0; s < 16; s++) {
    int nr = s * 4 + r0;
    xT[tbase + (size_t)nr * NC + j] = f2bf(T[j * 65 + nr]);
  }
}

// --------- generic B-transposed MFMA GEMM (frag-major LDS, dbuf) ------------
// C[b][m][n] = sum_k A[b][m][k]*Bt[b][n][k] (+bias)(relu)
// BIAS: 0 none, 1 bias[b*sbias+col], 2 bias[b*sbias+row]
template<int BM, int BN, int BK, int BIAS, bool RELU, bool OUTBF16>
__global__ __launch_bounds__(256) void gemm_bt_k(
    const u16* __restrict__ A, long long sA, int lda,
    const u16* __restrict__ Bt, long long sB, int ldb,
    void* __restrict__ C, long long sC, int ldc,
    int K, const float* __restrict__ bias, int sbias) {
  constexpr int TM = BM / 32, TN = BN / 32, KS = BK / 32;
  constexpr int ASZ = BM * BK, BSZ = BN * BK;
  __shared__ u16 As[2][ASZ];
  __shared__ u16 Bs[2][BSZ];
  const int b = blockIdx.z;
  const u16* Ab = A + (size_t)sA * b;
  const u16* Bb = Bt + (size_t)sB * b;
  const int m0 = blockIdx.x * BM, n0 = blockIdx.y * BN;
  const int tid = threadIdx.x, lane = tid & 63, wave = tid >> 6;
  const int q = lane >> 4, cc = lane & 15;
  const int wm = (wave >> 1) * (BM / 2), wn = (wave & 1) * (BN / 2);

  auto stage = [&](int p, int k0) {
    #pragma unroll
    for (int i = 0; i < ASZ / 2048; i++) {
      int slot = i * 256 + tid;
      int fr = slot / (64 * KS);
      int ks = (slot / 64) % KS;
      int qq = (slot >> 4) & 3, cq = slot & 15;
      lds_load16(Ab + (size_t)(m0 + fr * 16 + cq) * lda + k0 + ks * 32 + qq * 8,
                 &As[p][slot * 8]);
    }
    #pragma unroll
    for (int i = 0; i < BSZ / 2048; i++) {
      int slot = i * 256 + tid;
      int fr = slot / (64 * KS);
      int ks = (slot / 64) % KS;
      int qq = (slot >> 4) & 3, cq = slot & 15;
      lds_load16(Bb + (size_t)(n0 + fr * 16 + cq) * ldb + k0 + ks * 32 + qq * 8,
                 &Bs[p][slot * 8]);
    }
  };

  floatx4 acc[TM][TN];
  #pragma unroll
  for (int mi = 0; mi < TM; mi++)
    #pragma unroll
    for (int ni = 0; ni < TN; ni++)
      acc[mi][ni] = floatx4{0.f, 0.f, 0.f, 0.f};

  stage(0, 0);
  __syncthreads();
  int p = 0;
  for (int k0 = 0; k0 < K; k0 += BK) {
    if (k0 + BK < K) stage(p ^ 1, k0 + BK);
    #pragma unroll
    for (int ks = 0; ks < KS; ks++) {
      bfx8 af[TM], bfr[TN];
      #pragma unroll
      for (int mi = 0; mi < TM; mi++)
        af[mi] = *(const bfx8*)(&As[p][((((wm >> 4) + mi) * KS + ks) * 64 + lane) * 8]);
      #pragma unroll
      for (int ni = 0; ni < TN; ni++)
        bfr[ni] = *(const bfx8*)(&Bs[p][((((wn >> 4) + ni) * KS + ks) * 64 + lane) * 8]);
      #pragma unroll
      for (int mi = 0; mi < TM; mi++)
        #pragma unroll
        for (int ni = 0; ni < TN; ni++)
          acc[mi][ni] = mfma16(af[mi], bfr[ni], acc[mi][ni]);
    }
    __syncthreads();
    p ^= 1;
  }

  #pragma unroll
  for (int mi = 0; mi < TM; mi++) {
    #pragma unroll
    for (int ni = 0; ni < TN; ni++) {
      const int col = n0 + wn + ni * 16 + cc;
      #pragma unroll
      for (int r = 0; r < 4; r++) {
        int row = m0 + wm + mi * 16 + q * 4 + r;
        float v = acc[mi][ni][r];
        if constexpr (BIAS == 1) v += bias[b * sbias + col];
        if constexpr (BIAS == 2) v += bias[b * sbias + row];
        if constexpr (RELU) v = fmaxf(v, 0.f);
        size_t idx = (size_t)sC * b + (size_t)row * ldc + col;
        if constexpr (OUTBF16) ((u16*)C)[idx] = f2bf(v);
        else ((float*)C)[idx] = v;
      }
    }
  }
}

// ---- fused flash-style attention+output kernel ----
// Block owns 64 output columns m (= 64 rows of S). Loops k over 4096 in
// 64-wide tiles: S^T-tile = mfma(fT, gT) (rows=k, cols=m), exp -> E, E goes
// (a) to LDS in B-frag layout for the immediate out-MFMA
//     out[c][m] += h[c][k]*E[m][k],
// (b) to global pT (bf16) for the attn_norm pass.
// rsum[m] accumulates block-locally (block sees all k) -> no atomics; the
// epilogue applies gamma/rsum[m] + x residual. 8 waves: wave w: S-slice
// m16=w&3 x k-half=w>>2; out-slice c rows w*32..w*32+31 x all 64 m.
__global__ __launch_bounds__(512) void attn_out_k(
    const u16* __restrict__ gT, const u16* __restrict__ fT,
    const u16* __restrict__ hb, float* __restrict__ rs,
    u16* __restrict__ pT, float* __restrict__ out,
    const float* __restrict__ gamma, const float* __restrict__ x) {
  __shared__ u16 fTl[2][64 * 128];   // fT k-tile, frag-major, dbuf (32 KB)
  __shared__ u16 hl[256 * 64];       // h k-tile, frag-major (32 KB)
  __shared__ u32 EL[2048];           // E-tile 64m x 64k bf16, frag-major (8 KB)
  __shared__ float rsp[8][16];
  __shared__ float rsinv[64];
  const int b = blockIdx.z, m0 = blockIdx.x * 64;
  const int tid = threadIdx.x, lane = tid & 63, w = tid >> 6;
  const int q = lane >> 4, cc = lane & 15;
  const int khalf = w >> 2, m16w = w & 3;
  const size_t bN = (size_t)b * NSP;

  // gT rows for this wave's m16 (held in regs across the whole loop)
  bfx8 gB[4];
  {
    const u16* gA = gT + (bN + m0 + m16w * 16 + cc) * NCH;
    #pragma unroll
    for (int ks = 0; ks < 4; ks++) gB[ks] = *(const bfx8*)(gA + ks * 32 + q * 8);
  }

  floatx4 oacc[2][4];                // [cg][m16]
  #pragma unroll
  for (int cg = 0; cg < 2; cg++)
    #pragma unroll
    for (int m16 = 0; m16 < 4; m16++)
      oacc[cg][m16] = floatx4{0.f, 0.f, 0.f, 0.f};
  float ps = 0.f;

  // fT tile staging: chunk = ((fr*4 + ks)*64 + qq*16 + cq), 1024 slots
  auto stage_f = [&](int buf, int nt) {
    #pragma unroll
    for (int i = 0; i < 2; i++) {
      int slot = i * 512 + tid;
      int fr = slot >> 8, ks = (slot >> 6) & 3;
      int qq = (slot >> 4) & 3, cq = slot & 15;
      lds_load16(fT + (bN + nt + fr * 16 + cq) * NCH + ks * 32 + qq * 8,
                 &fTl[buf][slot * 8]);
    }
  };
  // h tile staging: chunk = ((fr*2 + ks)*64 + qq*16 + cq), 2048 slots
  auto stage_h = [&](int nt) {
    #pragma unroll
    for (int i = 0; i < 4; i++) {
      int slot = i * 512 + tid;
      int fr = slot >> 7, ks = (slot >> 6) & 1;
      int qq = (slot >> 4) & 3, cq = slot & 15;
      lds_load16(hb + ((size_t)b * NC + fr * 16 + cq) * NSP + nt + ks * 32 + qq * 8,
                 &hl[slot * 8]);
    }
  };

  stage_f(0, 0);
  __syncthreads();

  #pragma unroll 1
  for (int t = 0; t < 64; t++) {
    const int nt = t * 64;
    if (t + 1 < 64) stage_f((t + 1) & 1, nt + 64);   // prefetch next fT
    stage_h(nt);                                      // current h (async)

    // ---- S-phase: sacc[ni] = S^T rows k (this wave's 32) x cols m (16) ----
    floatx4 sacc[2];
    sacc[0] = floatx4{0.f, 0.f, 0.f, 0.f};
    sacc[1] = floatx4{0.f, 0.f, 0.f, 0.f};
    #pragma unroll
    for (int ks = 0; ks < 4; ks++) {
      #pragma unroll
      for (int ni = 0; ni < 2; ni++) {
        bfx8 a = *(const bfx8*)(&fTl[t & 1][(((khalf * 2 + ni) * 4 + ks) * 64 + lane) * 8]);
        sacc[ni] = mfma16(a, gB[ks], sacc[ni]);
      }
    }
    // exp + rsum partial + pack to EL (frag-major for the out-MFMA B-frags)
    // value at (k = khalf*32 + ni*16 + q*4 + r, m = m16w*16 + cc):
    //  -> u32 slot ((m16w*2 + khalf)*64 + (2*ni + (q>>1))*16 + cc)*4 + 2*(q&1)+r2
    #pragma unroll
    for (int ni = 0; ni < 2; ni++) {
      float e[4];
      #pragma unroll
      for (int r = 0; r < 4; r++) {
        e[r] = __expf(fminf(sacc[ni][r], 80.f));
        ps += e[r];
      }
      #pragma unroll
      for (int r2 = 0; r2 < 2; r2++) {
        u32 pk = (u32)f2bf(e[2 * r2]) | ((u32)f2bf(e[2 * r2 + 1]) << 16);
        EL[((m16w * 2 + khalf) * 64 + (2 * ni + (q >> 1)) * 16 + cc) * 4 +
           2 * (q & 1) + r2] = pk;
      }
    }
    __syncthreads();   // EL complete; h(t) arrived (vmcnt drained)

    // ---- out-phase: oacc[cg][m16] += h-frag * E-frag ----
    #pragma unroll
    for (int ks = 0; ks < 2; ks++) {
      bfx8 bf[4];
      #pragma unroll
      for (int m16 = 0; m16 < 4; m16++)
        bf[m16] = *(const bfx8*)((const u16*)&EL[((m16 * 2 + ks) * 64 + lane) * 4]);
      #pragma unroll
      for (int cg = 0; cg < 2; cg++) {
        bfx8 a = *(const bfx8*)(&hl[(((w * 2 + cg) * 2 + ks) * 64 + lane) * 8]);
        #pragma unroll
        for (int m16 = 0; m16 < 4; m16++)
          oacc[cg][m16] = mfma16(a, bf[m16], oacc[cg][m16]);
      }
    }
    // stream E-tile to pT: thread tid <-> EL chunk tid (16 B each)
    {
      const int fr = tid >> 7, ks2 = (tid >> 6) & 1;
      const int qv = (tid >> 4) & 3, cv = tid & 15;
      u32x4 d = *(const u32x4*)(&EL[tid * 4]);
      *(u32x4*)(pT + (bN + m0 + fr * 16 + cv) * NSP + nt + ks2 * 32 + qv * 8) = d;
    }
    __syncthreads();   // EL / hl / fTl[t&1] free for overwrite
  }

  // ---- rsum finalize (block-local, no atomics) ----
  ps += __shfl_xor(ps, 16, 64);
  ps += __shfl_xor(ps, 32, 64);
  if (lane < 16) rsp[w][lane] = ps;
  __syncthreads();
  if (tid < 64) {
    float s = rsp[tid >> 4][tid & 15] + rsp[4 + (tid >> 4)][tid & 15];
    rs[bN + m0 + tid] = s;
    rsinv[tid] = 1.f / s;
  }
  __syncthreads();

  // ---- epilogue: out = gamma * oacc / rsum[m] + x ----
  const float g0 = gamma[0];
  #pragma unroll
  for (int cg = 0; cg < 2; cg++) {
    #pragma unroll
    for (int m16 = 0; m16 < 4; m16++) {
      const float ri = rsinv[m16 * 16 + cc];
      #pragma unroll
      for (int r = 0; r < 4; r++) {
        int c = w * 32 + cg * 16 + q * 4 + r;
        int m = m16 * 16 + cc;
        size_t idx = ((size_t)b * NC + c) * NSP + m0 + m;
        out[idx] = g0 * oacc[cg][m16][r] * ri + x[idx];
      }
    }
  }
}

// ------- attn_norm: outP[b][n][m] = bf16 E[b][m][n] * (1/rsum[b][m]) -------
__global__ __launch_bounds__(256) void attn_norm_k(
    const u16* __restrict__ pT, const float* __restrict__ rs,
    float* __restrict__ outP) {
  __shared__ u16 T[64 * 257];
  __shared__ float rinvs[256];
  const int b = blockIdx.z, n0 = blockIdx.x * 64, m0 = blockIdx.y * 256;
  const int tid = threadIdx.x;
  const size_t bN = (size_t)b * NSP;

  rinvs[tid] = 1.f / rs[bN + m0 + tid];
  #pragma unroll
  for (int i = 0; i < 8; i++) {
    int slot = i * 256 + tid;
    int mi = slot >> 3, c8 = slot & 7;
    u16x8 v = *(const u16x8*)(pT + (bN + m0 + mi) * NSP + n0 + c8 * 8);
    #pragma unroll
    for (int j = 0; j < 8; j++) T[(c8 * 8 + j) * 257 + mi] = v[j];
  }
  __syncthreads();
  #pragma unroll
  for (int i = 0; i < 16; i++) {
    int slot = i * 256 + tid;
    int nl = slot >> 6, f4 = slot & 63;
    floatx4 rv = *(const floatx4*)(rinvs + f4 * 4);
    const u16* tr = T + nl * 257 + f4 * 4;
    floatx4 o;
    #pragma unroll
    for (int k = 0; k < 4; k++) o[k] = bf2f(tr[k]) * rv[k];
    *(floatx4*)(outP + (bN + n0 + nl) * NSP + m0 + f4 * 4) = o;
  }
}

// ---------------- launcher ----------------
extern "C" void kernel_launch(void* const* d_in, const int* in_sizes, int n_in,
                              void* d_out, int out_size, void* d_ws, size_t ws_size,
                              hipStream_t stream) {
  const float* x     = (const float*)d_in[0];
  const float* wf1   = (const float*)d_in[1];
  const float* bf1   = (const float*)d_in[2];
  const float* wf2   = (const float*)d_in[3];
  const float* bf2   = (const float*)d_in[4];
  const float* wg1   = (const float*)d_in[5];
  const float* bg1   = (const float*)d_in[6];
  const float* wg2   = (const float*)d_in[7];
  const float* bg2   = (const float*)d_in[8];
  const float* wh    = (const float*)d_in[9];
  const float* bh    = (const float*)d_in[10];
  const float* gamma = (const float*)d_in[11];
  float* out = (float*)d_out;

  char* ws = (char*)d_ws;
  size_t off = 0;
  auto alloc = [&](size_t bytes) -> char* {
    char* p = ws + off;
    off += (bytes + 255) & ~(size_t)255;
    return p;
  };
  u16* wfg1b = (u16*)alloc((size_t)256 * 256 * 2);       // [wf1;wg1]
  u16* wfg2b = (u16*)alloc((size_t)2 * 128 * 128 * 2);   // [wf2;wg2]
  u16* whb   = (u16*)alloc((size_t)NC * NC * 2);
  float* bfg1 = (float*)alloc(256 * 4);
  float* bfg2 = (float*)alloc(256 * 4);
  u16* xT   = (u16*)alloc((size_t)NB * NSP * NC * 2);    // (B,N,C)
  u16* fg1T = (u16*)alloc((size_t)NB * NSP * 256 * 2);   // (B*N, 256): f|g
  u16* fTb  = (u16*)alloc((size_t)NB * NSP * NCH * 2);
  u16* gTb  = (u16*)alloc((size_t)NB * NSP * NCH * 2);   // must follow fTb
  u16* hb   = (u16*)alloc((size_t)NB * NC * NSP * 2);    // (B,C,N)
  float* rs = (float*)alloc((size_t)NB * NSP * 4);       // row sums of E
  u16* pTb  = (u16*)alloc((size_t)NB * NSP * NSP * 2);   // E = exp(S), (B,m,n)

  cvt_all<<<dim3(641), 256, 0, stream>>>(wf1, wg1, wf2, wg2, wh,
                                         wfg1b, wfg2b, whb,
                                         bf1, bg1, bf2, bg2, bfg1, bfg2);
  transpose_x<<<dim3(NSP / 64, NC / 64, NB), 256, 0, stream>>>(x, xT);

  const long long sX = (long long)NSP * NC;
  const long long sH = (long long)NC * NSP;
  const long long sFG = (long long)NB * NSP * NCH;       // fTb -> gTb stride

  // fused f1|g1: (B*N,256) = relu(xT @ [wf1;wg1]^T + [bf1;bg1])
  gemm_bt_k<64, 128, 64, 1, true, true><<<dim3(256, 2, 1), 256, 0, stream>>>(
      xT, 0, NC, wfg1b, 0, NC, fg1T, 0, 256, NC, bfg1, 0);
  // fused f2/g2 via z-batch: z=0 -> fT from f half, z=1 -> gT from g half
  gemm_bt_k<64, 128, 64, 1, false, true><<<dim3(256, 1, 2), 256, 0, stream>>>(
      fg1T, 128, 256, wfg2b, 128 * 128, NCH, fTb, sFG, NCH, NCH, bfg2, 128);
  // h[b] = wh @ x[b] + bh
  gemm_bt_k<64, 128, 64, 2, false, true><<<dim3(4, 32, NB), 256, 0, stream>>>(
      whb, 0, NC, xT, sX, NC, hb, sH, NSP, NC, bh, 0);

  // fused: S -> E(pT) + rsum + out = gamma*(h@E)/rsum + x, one kernel
  attn_out_k<<<dim3(NSP / 64, 1, NB), 512, 0, stream>>>(
      gTb, fTb, hb, rs, pTb, out, gamma, x);

  // attn pass 2: normalized softmax output (transpose-scale, 1KB writes)
  attn_norm_k<<<dim3(NSP / 64, NSP / 256, NB), 256, 0, stream>>>(
      pTb, rs, out + OUT_OFF);

  (void)in_sizes; (void)n_in; (void)out_size; (void)ws_size;
}

// Round 6
// 512.591 us; speedup vs baseline: 1.0400x; 1.0400x over previous
//
#include <hip/hip_runtime.h>

typedef unsigned short u16;
typedef unsigned int   u32;
typedef float  floatx4 __attribute__((ext_vector_type(4)));
typedef __bf16 bfx8    __attribute__((ext_vector_type(8)));
typedef u16    u16x8   __attribute__((ext_vector_type(8)));

#define DEV __device__ __forceinline__

// Problem constants: B=4, C=256, Ch=128, N=H*W=4096
#define NB 4
#define NC 256
#define NCH 128
#define NSP 4096
#define OUT_OFF 4194304   // floats: 4*256*4096 out region precedes attn region
#define KSPL 2            // split-K factor for the final GEMM

DEV u16 f2bf(float f) {
  // native cast -> v_cvt_pk_bf16_f32 (RNE), 1 instr vs 4-op bit-munge
  return __builtin_bit_cast(u16, (__bf16)f);
}

DEV float bf2f(u16 h) {
  u32 w = (u32)h << 16;
  return __builtin_bit_cast(float, w);
}

DEV void lds_load16(const u16* g, u16* l) {
  __builtin_amdgcn_global_load_lds(
      (const __attribute__((address_space(1))) u32*)g,
      (__attribute__((address_space(3))) u32*)l, 16, 0, 0);
}

DEV floatx4 mfma16(bfx8 a, bfx8 b, floatx4 c) {
  return __builtin_amdgcn_mfma_f32_16x16x32_bf16(a, b, c, 0, 0, 0);
}

DEV float rsum16(float v) {
  #pragma unroll
  for (int m = 1; m < 16; m <<= 1) v += __shfl_xor(v, m, 64);
  return v;
}

// ------------- fused weight converter + prep (one launch) -------------------
// wfg1b = [wf1 ; wg1] (256x256), wfg2b = [wf2 ; wg2] (2 x 128x128), whb 256x256
// plus: rs zeroing, bias concat bfg1=[bf1;bg1], bfg2=[bf2;bg2]
__global__ __launch_bounds__(256) void cvt_all(
    const float* __restrict__ wf1, const float* __restrict__ wg1,
    const float* __restrict__ wf2, const float* __restrict__ wg2,
    const float* __restrict__ wh,
    u16* __restrict__ wfg1b, u16* __restrict__ wfg2b, u16* __restrict__ whb,
    float* __restrict__ rs,
    const float* __restrict__ bf1, const float* __restrict__ bg1,
    const float* __restrict__ bf2, const float* __restrict__ bg2,
    float* __restrict__ bfg1, float* __restrict__ bfg2) {
  int i = blockIdx.x * 256 + threadIdx.x;
  if (i < 32768) { wfg1b[i] = f2bf(wf1[i]); return; }
  i -= 32768;
  if (i < 32768) { wfg1b[32768 + i] = f2bf(wg1[i]); return; }
  i -= 32768;
  if (i < 16384) { wfg2b[i] = f2bf(wf2[i]); return; }
  i -= 16384;
  if (i < 16384) { wfg2b[16384 + i] = f2bf(wg2[i]); return; }
  i -= 16384;
  if (i < 65536) { whb[i] = f2bf(wh[i]); return; }
  i -= 65536;
  if (i < NB * NSP) { rs[i] = 0.f; return; }
  i -= NB * NSP;
  if (i < 128) { bfg1[i] = bf1[i]; return; }
  i -= 128;
  if (i < 128) { bfg1[128 + i] = bg1[i]; return; }
  i -= 128;
  if (i < 128) { bfg2[i] = bf2[i]; return; }
  i -= 128;
  if (i < 128) { bfg2[128 + i] = bg2[i]; return; }
}

// x (B,C,N) fp32 -> xT (B,N,C) bf16
__global__ __launch_bounds__(256) void transpose_x(const float* __restrict__ x,
                                                   u16* __restrict__ xT) {
  __shared__ float T[64 * 65];
  const int b = blockIdx.z, c0 = blockIdx.y * 64, n0 = blockIdx.x * 64;
  const int tid = threadIdx.x;
  const int j = tid & 63, r0 = tid >> 6;
  const size_t xbase = ((size_t)b * NC + c0) * NSP + n0;
  #pragma unroll
  for (int s = 0; s < 16; s++) {
    int cl = s * 4 + r0;
    T[cl * 65 + j] = x[xbase + (size_t)cl * NSP + j];
  }
  __syncthreads();
  const size_t tbase = ((size_t)b * NSP + n0) * NC + c0;
  #pragma unroll
  for (int s = 0; s < 16; s++) {
    int nr = s * 4 + r0;
    xT[tbase + (size_t)nr * NC + j] = f2bf(T[j * 65 + nr]);
  }
}

// --------- generic B-transposed MFMA GEMM (frag-major LDS, 1-buf) -----------
// C[z][m][n] = sum_k A[b][m][kc*K+k]*Bt[b][n][kc*K+k] (+bias)(relu)
//   where (KSP>1): b = z/KSP, kc = z%KSP  (split-K partial store, fp32)
// BIAS: 0 none, 1 bias[b*sbias+col], 2 bias[b*sbias+row]
// SWZ: bijective XCD-chunk swizzle (requires total blocks % 8 == 0)
template<int BM, int BN, int BK, int BIAS, bool RELU, bool OUTBF16, int KSP,
         bool SWZ>
__global__ __launch_bounds__(256) void gemm_bt_k(
    const u16* __restrict__ A, long long sA, int lda,
    const u16* __restrict__ Bt, long long sB, int ldb,
    void* __restrict__ C, long long sC, int ldc,
    int K, const float* __restrict__ bias, int sbias) {
  constexpr int TM = BM / 32, TN = BN / 32, KS = BK / 32;
  __shared__ u16 As[BM * BK];
  __shared__ u16 Bs[BN * BK];
  int bx = blockIdx.x, by = blockIdx.y, bz = blockIdx.z;
  if constexpr (SWZ) {
    const int gx = gridDim.x, gy = gridDim.y;
    const int nwg = gx * gy * gridDim.z;
    const int bid = (bz * gy + by) * gx + bx;
    const int lx = (bid & 7) * (nwg >> 3) + (bid >> 3);
    bx = lx % gx;
    const int t = lx / gx;
    by = t % gy;
    bz = t / gy;
  }
  const int b = (KSP > 1) ? bz / KSP : bz;
  const int kc = (KSP > 1) ? bz % KSP : 0;
  const u16* Ab = A + (size_t)sA * b + (size_t)kc * K;
  const u16* Bb = Bt + (size_t)sB * b + (size_t)kc * K;
  const int m0 = bx * BM, n0 = by * BN;
  const int tid = threadIdx.x, lane = tid & 63, wave = tid >> 6;
  const int q = lane >> 4, cc = lane & 15;
  const int wm = (wave >> 1) * (BM / 2), wn = (wave & 1) * (BN / 2);

  floatx4 acc[TM][TN];
  #pragma unroll
  for (int mi = 0; mi < TM; mi++)
    #pragma unroll
    for (int ni = 0; ni < TN; ni++)
      acc[mi][ni] = floatx4{0.f, 0.f, 0.f, 0.f};

  for (int k0 = 0; k0 < K; k0 += BK) {
    // frag-major staging: LDS chunk index = (frag_row*KS + ks)*64 + lane
    #pragma unroll
    for (int i = 0; i < BM * BK / 2048; i++) {
      int slot = i * 256 + tid;
      int fr = slot / (64 * KS);
      int ks = (slot / 64) % KS;
      int qq = (slot >> 4) & 3, cq = slot & 15;
      lds_load16(Ab + (size_t)(m0 + fr * 16 + cq) * lda + k0 + ks * 32 + qq * 8,
                 As + slot * 8);
    }
    #pragma unroll
    for (int i = 0; i < BN * BK / 2048; i++) {
      int slot = i * 256 + tid;
      int fr = slot / (64 * KS);
      int ks = (slot / 64) % KS;
      int qq = (slot >> 4) & 3, cq = slot & 15;
      lds_load16(Bb + (size_t)(n0 + fr * 16 + cq) * ldb + k0 + ks * 32 + qq * 8,
                 Bs + slot * 8);
    }
    __syncthreads();
    #pragma unroll
    for (int ks = 0; ks < KS; ks++) {
      bfx8 af[TM], bfr[TN];
      #pragma unroll
      for (int mi = 0; mi < TM; mi++)
        af[mi] = *(const bfx8*)(As + ((((wm >> 4) + mi) * KS + ks) * 64 + lane) * 8);
      #pragma unroll
      for (int ni = 0; ni < TN; ni++)
        bfr[ni] = *(const bfx8*)(Bs + ((((wn >> 4) + ni) * KS + ks) * 64 + lane) * 8);
      #pragma unroll
      for (int mi = 0; mi < TM; mi++)
        #pragma unroll
        for (int ni = 0; ni < TN; ni++)
          acc[mi][ni] = mfma16(af[mi], bfr[ni], acc[mi][ni]);
    }
    __syncthreads();
  }

  #pragma unroll
  for (int mi = 0; mi < TM; mi++) {
    #pragma unroll
    for (int ni = 0; ni < TN; ni++) {
      const int col = n0 + wn + ni * 16 + cc;    // C/D: col=lane&15
      #pragma unroll
      for (int r = 0; r < 4; r++) {
        int row = m0 + wm + mi * 16 + q * 4 + r; // C/D: row=(lane>>4)*4+reg
        float v = acc[mi][ni][r];
        if constexpr (BIAS == 1) v += bias[b * sbias + col];
        if constexpr (BIAS == 2) v += bias[b * sbias + row];
        if constexpr (RELU) v = fmaxf(v, 0.f);
        size_t idx = (size_t)sC * bz + (size_t)row * ldc + col;
        if constexpr (OUTBF16) ((u16*)C)[idx] = f2bf(v);
        else ((float*)C)[idx] = v;
      }
    }
  }
}

// ------- attn pass 1: S once; pT = exp(S) bf16 (UNNORMALIZED); rsum atomic --
__global__ __launch_bounds__(256) void attn_se_k(
    const u16* __restrict__ gT, const u16* __restrict__ fT,
    float* __restrict__ rsum, u16* __restrict__ pT) {
  __shared__ u16 Bs[64 * 128];
  __shared__ u16 Pb[64 * 72];
  const int b = blockIdx.z, m0 = blockIdx.y * 64, n0 = blockIdx.x * 512;
  const int tid = threadIdx.x, lane = tid & 63, wave = tid >> 6;
  const int q = lane >> 4, cc = lane & 15;
  const size_t bN = (size_t)b * NSP;

  bfx8 af[4];
  {
    const u16* gA = gT + (bN + m0 + wave * 16 + cc) * NCH;
    #pragma unroll
    for (int ks = 0; ks < 4; ks++) af[ks] = *(const bfx8*)(gA + ks * 32 + q * 8);
  }
  float ps[4] = {0.f, 0.f, 0.f, 0.f};

  for (int sc = 0; sc < 8; sc++) {
    const int nc = n0 + sc * 64;
    #pragma unroll
    for (int i = 0; i < 4; i++) {
      int slot = i * 256 + tid;
      int ni = slot >> 8, ks = (slot >> 6) & 3;
      int qq = (slot >> 4) & 3, cq = slot & 15;
      lds_load16(fT + (bN + nc + ni * 16 + cq) * NCH + ks * 32 + qq * 8,
                 Bs + slot * 8);
    }
    __syncthreads();
    #pragma unroll
    for (int ni = 0; ni < 4; ni++) {
      floatx4 s = floatx4{0.f, 0.f, 0.f, 0.f};
      #pragma unroll
      for (int ks = 0; ks < 4; ks++) {
        bfx8 bfr = *(const bfx8*)(Bs + ((ni * 4 + ks) * 64 + lane) * 8);
        s = mfma16(af[ks], bfr, s);
      }
      #pragma unroll
      for (int r = 0; r < 4; r++) {
        float e = __expf(fminf(s[r], 80.f));
        ps[r] += e;
        Pb[(wave * 16 + q * 4 + r) * 72 + ni * 16 + cc] = f2bf(e);
      }
    }
    __syncthreads();
    #pragma unroll
    for (int i = 0; i < 2; i++) {
      int slot = i * 256 + tid;
      int ml = slot >> 3, c8 = slot & 7;
      u16x8 v = *(const u16x8*)(Pb + ml * 72 + c8 * 8);
      *(u16x8*)(pT + (bN + m0 + ml) * NSP + nc + c8 * 8) = v;
    }
    // next iteration's post-stage barrier orders Pb reads before Pb rewrites
  }
  #pragma unroll
  for (int r = 0; r < 4; r++) ps[r] = rsum16(ps[r]);
  if (cc == 0) {
    #pragma unroll
    for (int r = 0; r < 4; r++)
      atomicAdd(&rsum[bN + m0 + wave * 16 + q * 4 + r], ps[r]);
  }
}

// ------- split-K reduce: out = gamma*(p0+p1)/rs[m] + x ----------------------
__global__ __launch_bounds__(256) void reduce_out_k(
    const float* __restrict__ part, const float* __restrict__ rs,
    const float* __restrict__ x, const float* __restrict__ gamma,
    float* __restrict__ out) {
  const float g0 = gamma[0];
  const size_t idx = ((size_t)blockIdx.x * 256 + threadIdx.x) * 4;
  const int m = (int)(idx & (NSP - 1));
  const int b = (int)(idx >> 20);                 // /(256*4096)
  const size_t inner = idx & (((size_t)1 << 20) - 1);
  const size_t SC = (size_t)NC * NSP;
  floatx4 p0 = *(const floatx4*)(part + (size_t)(b * KSPL) * SC + inner);
  floatx4 p1 = *(const floatx4*)(part + (size_t)(b * KSPL + 1) * SC + inner);
  floatx4 xr = *(const floatx4*)(x + idx);
  floatx4 rv = *(const floatx4*)(rs + (size_t)b * NSP + m);
  floatx4 o;
  #pragma unroll
  for (int k = 0; k < 4; k++) o[k] = g0 * (p0[k] + p1[k]) / rv[k] + xr[k];
  *(floatx4*)(out + idx) = o;
}

// ------- attn_norm: outP[b][n][m] = bf16 E[b][m][n] * (1/rsum[b][m]) -------
// 64n x 256m tile; transpose on the LDS write side; 1 KB contiguous HBM rows.
__global__ __launch_bounds__(256) void attn_norm_k(
    const u16* __restrict__ pT, const float* __restrict__ rs,
    float* __restrict__ outP) {
  __shared__ u16 T[64 * 257];
  __shared__ float rinvs[256];
  const int b = blockIdx.z, n0 = blockIdx.x * 64, m0 = blockIdx.y * 256;
  const int tid = threadIdx.x;
  const size_t bN = (size_t)b * NSP;

  rinvs[tid] = 1.f / rs[bN + m0 + tid];
  #pragma unroll
  for (int i = 0; i < 8; i++) {
    int slot = i * 256 + tid;
    int mi = slot >> 3, c8 = slot & 7;
    u16x8 v = *(const u16x8*)(pT + (bN + m0 + mi) * NSP + n0 + c8 * 8);
    #pragma unroll
    for (int j = 0; j < 8; j++) T[(c8 * 8 + j) * 257 + mi] = v[j];
  }
  __syncthreads();
  #pragma unroll
  for (int i = 0; i < 16; i++) {
    int slot = i * 256 + tid;
    int nl = slot >> 6, f4 = slot & 63;
    floatx4 rv = *(const floatx4*)(rinvs + f4 * 4);
    const u16* tr = T + nl * 257 + f4 * 4;
    floatx4 o;
    #pragma unroll
    for (int k = 0; k < 4; k++) o[k] = bf2f(tr[k]) * rv[k];
    *(floatx4*)(outP + (bN + n0 + nl) * NSP + m0 + f4 * 4) = o;
  }
}

// ---------------- launcher ----------------
extern "C" void kernel_launch(void* const* d_in, const int* in_sizes, int n_in,
                              void* d_out, int out_size, void* d_ws, size_t ws_size,
                              hipStream_t stream) {
  const float* x     = (const float*)d_in[0];
  const float* wf1   = (const float*)d_in[1];
  const float* bf1   = (const float*)d_in[2];
  const float* wf2   = (const float*)d_in[3];
  const float* bf2   = (const float*)d_in[4];
  const float* wg1   = (const float*)d_in[5];
  const float* bg1   = (const float*)d_in[6];
  const float* wg2   = (const float*)d_in[7];
  const float* bg2   = (const float*)d_in[8];
  const float* wh    = (const float*)d_in[9];
  const float* bh    = (const float*)d_in[10];
  const float* gamma = (const float*)d_in[11];
  float* out = (float*)d_out;

  char* ws = (char*)d_ws;
  size_t off = 0;
  auto alloc = [&](size_t bytes) -> char* {
    char* p = ws + off;
    off += (bytes + 255) & ~(size_t)255;
    return p;
  };
  u16* wfg1b = (u16*)alloc((size_t)256 * 256 * 2);       // [wf1;wg1]
  u16* wfg2b = (u16*)alloc((size_t)2 * 128 * 128 * 2);   // [wf2;wg2]
  u16* whb   = (u16*)alloc((size_t)NC * NC * 2);
  float* bfg1 = (float*)alloc(256 * 4);
  float* bfg2 = (float*)alloc(256 * 4);
  u16* xT   = (u16*)alloc((size_t)NB * NSP * NC * 2);    // (B,N,C)
  u16* fg1T = (u16*)alloc((size_t)NB * NSP * 256 * 2);   // (B*N, 256): f|g
  u16* fTb  = (u16*)alloc((size_t)NB * NSP * NCH * 2);
  u16* gTb  = (u16*)alloc((size_t)NB * NSP * NCH * 2);   // must follow fTb
  u16* hb   = (u16*)alloc((size_t)NB * NC * NSP * 2);    // (B,C,N)
  float* rs = (float*)alloc((size_t)NB * NSP * 4);       // row sums of E
  u16* pTb  = (u16*)alloc((size_t)NB * NSP * NSP * 2);   // E = exp(S), (B,m,n)
  float* part = (float*)alloc((size_t)NB * KSPL * NC * NSP * 4);  // splitK

  // 163840 weight elems + 16384 rs + 512 bias = 180736 -> 707 blocks
  cvt_all<<<dim3(707), 256, 0, stream>>>(wf1, wg1, wf2, wg2, wh,
                                         wfg1b, wfg2b, whb,
                                         rs, bf1, bg1, bf2, bg2, bfg1, bfg2);
  transpose_x<<<dim3(NSP / 64, NC / 64, NB), 256, 0, stream>>>(x, xT);

  const long long sX = (long long)NSP * NC;
  const long long sH = (long long)NC * NSP;
  const long long sP = (long long)NSP * NSP;
  const long long sFG = (long long)NB * NSP * NCH;       // fTb -> gTb stride

  // fused f1|g1: (B*N,256) = relu(xT @ [wf1;wg1]^T + [bf1;bg1])
  gemm_bt_k<64, 128, 64, 1, true, true, 1, false>
      <<<dim3(256, 2, 1), 256, 0, stream>>>(
      xT, 0, NC, wfg1b, 0, NC, fg1T, 0, 256, NC, bfg1, 0);
  // fused f2/g2 via z-batch: z=0 -> fT from f half, z=1 -> gT from g half
  gemm_bt_k<64, 128, 64, 1, false, true, 1, false>
      <<<dim3(256, 1, 2), 256, 0, stream>>>(
      fg1T, 128, 256, wfg2b, 128 * 128, NCH, fTb, sFG, NCH, NCH, bfg2, 128);
  // h[b] = wh @ x[b] + bh
  gemm_bt_k<64, 128, 64, 2, false, true, 1, false>
      <<<dim3(4, 32, NB), 256, 0, stream>>>(
      whb, 0, NC, xT, sX, NC, hb, sH, NSP, NC, bh, 0);

  // attn pass 1: E = exp(S) bf16 + row sums (single S computation)
  attn_se_k<<<dim3(8, 64, NB), 256, 0, stream>>>(gTb, fTb, rs, pTb);

  // split-K partials: part[b*2+kc] = h[b][:, kc*2048:+2048] @ E[b][:, same]^T
  // grid (2,64,8) = 1024 blocks = 4/CU (LDS 24KB -> all resident); XCD swizzle
  // groups tiles sharing h/pT slabs per XCD L2.
  gemm_bt_k<128, 64, 64, 0, false, false, KSPL, true>
      <<<dim3(2, 64, NB * KSPL), 256, 0, stream>>>(
      hb, sH, NSP, pTb, sP, NSP, part, sH, NSP, NSP / KSPL, nullptr, 0);

  // reduce: out = gamma*(p0+p1)/rs[m] + x   (4.19M floats, float4/thread)
  reduce_out_k<<<dim3(4096), 256, 0, stream>>>(part, rs, x, gamma, out);

  // attn pass 2: normalized softmax output (transpose-scale, 1KB writes)
  attn_norm_k<<<dim3(NSP / 64, NSP / 256, NB), 256, 0, stream>>>(
      pTb, rs, out + OUT_OFF);

  (void)in_sizes; (void)n_in; (void)out_size; (void)ws_size;
}